// Round 2
// baseline (194.573 us; speedup 1.0000x reference)
//
#include <hip/hip_runtime.h>
#include <cstdint>
#include <cstddef>

#define S 8192
#define Dm 1024
#define E 64
#define CAP 128
#define SEC 67108864   // S*E*CAP
// out layout (float32 elements):
//   [0]                 l_aux
//   [1 .. 1+SEC)        combine_weights
//   [1+SEC .. 1+2*SEC)  dispatch_mask (0.0/1.0)
//   [1+2*SEC .. +64)    exp_counts (as float)
// out_size = 1 + 2*SEC + 64 = 134,217,793 floats

#define GEMM_BLOCKS 256
#define FILL_BLOCKS 2048
#define NT 256

// ---------------- K1: fused logits GEMM + 537MB zero-fill ----------------
// Blocks [0,256): GEMM. 256 threads = 256 tokens/block, 8 experts/thread.
//   32 token-tiles x 8 expert-groups; tt = bid&31 so the 8 expert-group
//   sharers of a tile are 32 apart (same XCD under bid%8 round-robin).
//   Weights are wave-uniform indexed -> scalar-cache loads.
// Blocks [256,2304): grid-stride float4 zero-fill of the whole output.
//   The fill is HBM-write-bound (~85us); the GEMM hides under it.
__global__ __launch_bounds__(256) void k_gemm_fill(const float* __restrict__ x,
                                                   const float* __restrict__ w,
                                                   float* __restrict__ logits,
                                                   float* __restrict__ out,
                                                   float* __restrict__ me_sum) {
    int bid = blockIdx.x;
    int tid = threadIdx.x;
    if (bid < GEMM_BLOCKS) {
        int tt = bid & 31;
        int et = bid >> 5;
        int m = tt * 256 + tid;
        const float* arow = x + (size_t)m * Dm;
        const float* wbase = w + (size_t)(et * 8) * Dm;
        float acc[8] = {0.f, 0.f, 0.f, 0.f, 0.f, 0.f, 0.f, 0.f};
        for (int kc = 0; kc < Dm; kc += 8) {
            float4 a0 = *(const float4*)(arow + kc);
            float4 a1 = *(const float4*)(arow + kc + 4);
            float a[8] = {a0.x, a0.y, a0.z, a0.w, a1.x, a1.y, a1.z, a1.w};
#pragma unroll
            for (int kk = 0; kk < 8; ++kk) {
#pragma unroll
                for (int n = 0; n < 8; ++n) {
                    acc[n] = fmaf(a[kk], wbase[(size_t)n * Dm + kc + kk], acc[n]);
                }
            }
        }
        float* lrow = logits + (size_t)m * E + et * 8;
#pragma unroll
        for (int n = 0; n < 8; ++n) lrow[n] = acc[n];
    } else {
        int fb = bid - GEMM_BLOCKS;
        if (fb == 0 && tid < E) me_sum[tid] = 0.f;
        float4 z = make_float4(0.f, 0.f, 0.f, 0.f);
        float4* o4 = (float4*)out;
        const unsigned N4 = (1u + 2u * SEC + 64u) / 4u;   // 33,554,448 float4s
        for (unsigned i = (unsigned)fb * NT + tid; i < N4; i += FILL_BLOCKS * NT)
            o4[i] = z;
        if (fb == 0 && tid == 0) out[2 * SEC] = 0.f;      // last element (idx 134,217,792)
    }
}

// ---------------- K2: per-token softmax/argmax + column sums ----------------
// 128 blocks x 64 threads; tile 64x64 logits in LDS (pad 65).
__global__ __launch_bounds__(64) void k_softmax(const float* __restrict__ logits,
                                                float* __restrict__ gate,
                                                int* __restrict__ idx,
                                                float* __restrict__ me_sum) {
    __shared__ float tile[64][65];
    __shared__ float sm[64];
    __shared__ float sinv[64];
    int t0 = blockIdx.x * 64;
    int tid = threadIdx.x;
    for (int it = 0; it < 16; ++it) {
        int row = it * 4 + (tid >> 4);
        int c4 = (tid & 15) * 4;
        float4 v = *(const float4*)(logits + (size_t)(t0 + row) * E + c4);
        tile[row][c4 + 0] = v.x;
        tile[row][c4 + 1] = v.y;
        tile[row][c4 + 2] = v.z;
        tile[row][c4 + 3] = v.w;
    }
    __syncthreads();
    {   // row phase: first-index argmax + exp-sum
        int r = tid;
        float m = tile[r][0];
        int am = 0;
#pragma unroll
        for (int c = 1; c < E; ++c) {
            float v = tile[r][c];
            if (v > m) { m = v; am = c; }
        }
        float ssum = 0.f;
#pragma unroll
        for (int c = 0; c < E; ++c) ssum += __expf(tile[r][c] - m);
        float inv = 1.0f / ssum;
        gate[t0 + r] = inv;
        idx[t0 + r] = am;
        sm[r] = m;
        sinv[r] = inv;
    }
    __syncthreads();
    {   // column phase: per-expert softmax column sums (for me)
        int c = tid;
        float cs = 0.f;
#pragma unroll 8
        for (int r = 0; r < 64; ++r) cs += __expf(tile[r][c] - sm[r]) * sinv[r];
        atomicAdd(&me_sum[c], cs);
    }
}

// ---------------- K3: ordered scan + scatter + counts + l_aux ----------------
// 64 blocks (one per expert) x 256 threads; deterministic ballot scan in
// token order; scatters combine/dispatch inline (out is already zeroed).
__global__ __launch_bounds__(256) void k_scan(const int* __restrict__ idx,
                                              const float* __restrict__ gate,
                                              const float* __restrict__ me_sum,
                                              float* __restrict__ out) {
    int e = blockIdx.x;
    int tid = threadIdx.x;
    int lane = tid & 63;
    int wid = tid >> 6;
    __shared__ int wsum[4];
    int running = 0;
    for (int ch = 0; ch < S / 256; ++ch) {
        int t = ch * 256 + tid;
        bool f = (idx[t] == e);
        unsigned long long b = __ballot(f);
        int pre = __popcll(b & ((1ull << lane) - 1ull));
        if (lane == 0) wsum[wid] = __popcll(b);
        __syncthreads();
        int off = running;
#pragma unroll
        for (int w2 = 0; w2 < 4; ++w2)
            if (w2 < wid) off += wsum[w2];
        int p = off + pre;
        if (f && p < CAP) {
            size_t o = 1 + (size_t)t * (E * CAP) + (size_t)e * CAP + (size_t)p;
            out[o] = gate[t];                 // combine_weights
            out[o + (size_t)SEC] = 1.0f;      // dispatch_mask
        }
        running += wsum[0] + wsum[1] + wsum[2] + wsum[3];
        __syncthreads();
    }
    if (tid == 0) {
        out[1 + 2 * (size_t)SEC + e] = (float)running;   // exp_counts (pre-drop)
        float la = me_sum[e] * (1.0f / (float)S) *
                   ((float)running / (float)S) * (float)E;
        atomicAdd(out, la);                              // l_aux
    }
}

extern "C" void kernel_launch(void* const* d_in, const int* in_sizes, int n_in,
                              void* d_out, int out_size, void* d_ws, size_t ws_size,
                              hipStream_t stream) {
    const float* x = (const float*)d_in[0];      // [S, Dm] fp32
    const float* w = (const float*)d_in[1];      // [E, Dm] fp32
    float* out = (float*)d_out;

    // ws layout
    float* logits = (float*)d_ws;                // S*E floats
    float* gate = logits + (size_t)S * E;        // S floats
    int* idx = (int*)(gate + S);                 // S ints
    float* me_sum = (float*)(idx + S);           // E floats

    k_gemm_fill<<<dim3(GEMM_BLOCKS + FILL_BLOCKS), dim3(NT), 0, stream>>>(
        x, w, logits, out, me_sum);
    k_softmax<<<dim3(128), dim3(64), 0, stream>>>(logits, gate, idx, me_sum);
    k_scan<<<dim3(64), dim3(256), 0, stream>>>(idx, gate, me_sum, out);
}